// Round 20
// baseline (160.023 us; speedup 1.0000x reference)
//
#include <hip/hip_runtime.h>
#include <hip/hip_bf16.h>

// Problem constants
#define NPIX 12544   // 112*112
#define NKV 196      // 14*14
#define CCH 64

typedef _Float16 half2_t __attribute__((ext_vector_type(2)));
typedef _Float16 half4_t __attribute__((ext_vector_type(4)));
typedef float float4_t __attribute__((ext_vector_type(4)));
typedef __fp16 fp16v2_t __attribute__((ext_vector_type(2)));

#if defined(__has_builtin)
#if __has_builtin(__builtin_amdgcn_fdot2)
#define HAVE_FDOT2 1
#endif
#if __has_builtin(__builtin_amdgcn_cvt_pkrtz)
#define HAVE_PKRTZ 1
#endif
#if __has_builtin(__builtin_amdgcn_exp2f)
#define HAVE_EXP2 1
#endif
#if __has_builtin(__builtin_amdgcn_mfma_f32_16x16x16f16)
#define HAVE_MFMA16 1
#endif
#endif

__device__ __forceinline__ float dot2acc(half2_t a, half2_t b, float c) {
#ifdef HAVE_FDOT2
  return __builtin_amdgcn_fdot2(a, b, c, false);
#else
  return c + (float)a.x * (float)b.x + (float)a.y * (float)b.y;
#endif
}

__device__ __forceinline__ half2_t pack2(float a, float b) {
#ifdef HAVE_PKRTZ
  union { fp16v2_t r; half2_t h; } u;
  u.r = __builtin_amdgcn_cvt_pkrtz(a, b);
  return u.h;
#else
  half2_t v; v.x = (_Float16)a; v.y = (_Float16)b; return v;
#endif
}

__device__ __forceinline__ half2_t as_h2(uint u) {
  union { uint v; half2_t h; } c; c.v = u; return c.h;
}
__device__ __forceinline__ uint h2u(half2_t h) {
  union { half2_t h; uint v; } c; c.h = h; return c.v;
}
__device__ __forceinline__ float fexp2(float x) {
#ifdef HAVE_EXP2
  return __builtin_amdgcn_exp2f(x);
#else
  return exp2f(x);
#endif
}

__device__ __forceinline__ float4_t mfma16(half4_t a, half4_t b, float4_t c) {
#ifdef HAVE_MFMA16
  return __builtin_amdgcn_mfma_f32_16x16x16f16(a, b, c, 0, 0, 0);
#else
  asm volatile("v_mfma_f32_16x16x16_f16 %0, %1, %2, %0" : "+v"(c) : "v"(a), "v"(b));
  return c;
#endif
}

union U2H4 { uint2 u; half4_t h; };

// q scale: hd^-0.5 * log2(e) so the softmax can use raw exp2 (v_exp_f32)
#define QSCALE 0.5100974012336431f

// ---------------------------------------------------------------------------
// Prep kernel (R13): transpose x1/x2; srw -> wt f32 [ij][ci][co]; wcomb;
// pwv -> pwh f16 [c2][co].
__global__ __launch_bounds__(256) void k_prep(
    const float* __restrict__ x1, const float* __restrict__ x2,
    float* __restrict__ x1f, float* __restrict__ x2f,
    const float* __restrict__ s0, const float* __restrict__ s1,
    const float* __restrict__ s2, const float* __restrict__ s3,
    float* __restrict__ wt,
    const float* __restrict__ fpw, const float* __restrict__ fpb,
    const float* __restrict__ pw4, const float* __restrict__ pb4,
    const float* __restrict__ pw0, const float* __restrict__ pw1,
    const float* __restrict__ pw2,
    uint* __restrict__ pwh, float* __restrict__ pbc) {
  __shared__ float smem[2 * 64 * 65 + 64];
  int blk = blockIdx.x, t = threadIdx.x;
  float (*tile)[65] = (float(*)[65])smem;
  if (blk < 784) {
    int tensor = blk / 392; int rem = blk - tensor * 392;
    int b = rem / 196; int t64 = rem % 196; int n0 = t64 * 64;
    const float* src = tensor ? x2 : x1;
    float* dst = tensor ? x2f : x1f;
    for (int i = 0; i < 16; ++i) {
      int c = i * 4 + (t >> 6);
      int n = t & 63;
      tile[c][n] = src[(b * 64 + c) * NPIX + n0 + n];
    }
    __syncthreads();
    for (int i = 0; i < 16; ++i) {
      int n = i * 4 + (t >> 6);
      int c = t & 63;
      dst[(b * NPIX + n0 + n) * 64 + c] = tile[c][n];
    }
  } else if (blk < 1040) {
    int id = blk - 784; int a = id >> 6; int ci = id & 63;
    const float* s = (a == 0) ? s0 : (a == 1) ? s1 : (a == 2) ? s2 : s3;
    float* d = wt + a * 262144;
    for (int i = 0; i < 16; ++i) {
      int co = i * 4 + (t >> 6);
      int ij = t & 63;
      tile[co][ij] = s[co * 4096 + ci * 64 + ij];
    }
    __syncthreads();
    for (int i = 0; i < 16; ++i) {
      int ij = i * 4 + (t >> 6);
      int co = t & 63;
      d[(ij * 64 + ci) * 64 + co] = tile[co][ij];
    }
  } else if (blk == 1040) {
    float (*A)[65] = (float(*)[65])smem;
    float (*B)[65] = (float(*)[65])(smem + 4160);
    float* bb = smem + 8320;
    for (int i = 0; i < 16; ++i) {
      int idx = i * 256 + t;
      A[idx >> 6][idx & 63] = fpw[idx];
      B[idx >> 6][idx & 63] = pw4[idx];
    }
    if (t < 64) bb[t] = pb4[t];
    __syncthreads();
    int i = t >> 2, jq = t & 3;
    float acc[16];
#pragma unroll
    for (int jj = 0; jj < 16; ++jj) acc[jj] = 0.f;
    for (int k = 0; k < 64; ++k) {
      float a = A[i][k];
#pragma unroll
      for (int jj = 0; jj < 16; ++jj) acc[jj] += a * B[k][jq * 16 + jj];
    }
#pragma unroll
    for (int m = 0; m < 8; ++m)
      pwh[3 * 2048 + (jq * 8 + m) * 64 + i] = h2u(pack2(acc[2 * m], acc[2 * m + 1]));
    if (t < 64) {
      float s = fpb[t];
      for (int k = 0; k < 64; ++k) s += A[t][k] * bb[k];
      pbc[t] = s;
    }
  } else {
    int a = blk - 1041;
    const float* pw = (a == 0) ? pw0 : (a == 1) ? pw1 : pw2;
    for (int i = 0; i < 8; ++i) {
      int idx = i * 256 + t;
      int co = idx & 63, c2 = idx >> 6;
      float2 wv = *(const float2*)(pw + co * 64 + c2 * 2);
      pwh[a * 2048 + c2 * 64 + co] = h2u(pack2(wv.x, wv.y));
    }
  }
}

// ---------------------------------------------------------------------------
// Reduction conv as GEMM partials (R13).  grid = 49 groups * 8 k-slices.
__global__ __launch_bounds__(256) void k_conv(
    const float* __restrict__ xf, const float* __restrict__ wt,
    float* __restrict__ part) {
  __shared__ __align__(16) float act[8 * 8 * 72];
  __shared__ float red[16][8][65];
  int g = blockIdx.x % 49, s = blockIdx.x / 49;
  int t = threadIdx.x;
  for (int q = 0; q < 5; ++q) {
    int fi = q * 256 + t;
    if (fi < 1152) {
      int row = fi / 18, pos = fi % 18;
      if (pos < 16) {
        int pix = row >> 3, ijl = row & 7;
        int ij = s * 8 + ijl, ii = ij >> 3, jj = ij & 7;
        int p = g * 8 + pix, b = p / 196, pi = p % 196;
        int py = pi / 14, px = pi % 14;
        *(float4*)&act[row * 72 + pos * 4] =
            *(const float4*)(xf + (size_t)(b * NPIX + (8 * py + ii) * 112 + 8 * px + jj) * 64 + pos * 4);
      }
    }
  }
  __syncthreads();
  int coq = t & 15, kp = t >> 4;
  int ijl = kp >> 1, ci0 = (kp & 1) * 32;
  float acc[8][4];
#pragma unroll
  for (int p = 0; p < 8; ++p)
#pragma unroll
    for (int c = 0; c < 4; ++c) acc[p][c] = 0.f;
  const float* wb = wt + ((s * 8 + ijl) * 64 + ci0) * 64 + coq * 4;
  const float* ab = act + ijl * 72 + ci0;
  for (int kk = 0; kk < 32; ++kk) {
    float4 w4 = *(const float4*)(wb + kk * 64);
#pragma unroll
    for (int p = 0; p < 8; ++p) {
      float a = ab[p * 576 + kk];
      acc[p][0] += a * w4.x; acc[p][1] += a * w4.y;
      acc[p][2] += a * w4.z; acc[p][3] += a * w4.w;
    }
  }
#pragma unroll
  for (int p = 0; p < 8; ++p)
#pragma unroll
    for (int c = 0; c < 4; ++c) red[kp][p][coq * 4 + c] = acc[p][c];
  __syncthreads();
  for (int q = 0; q < 2; ++q) {
    int oi = t + q * 256;
    int pix = oi >> 6, co = oi & 63;
    float sum = 0.f;
#pragma unroll
    for (int k = 0; k < 16; ++k) sum += red[k][pix][co];
    int p = g * 8 + pix;
    part[(s * 392 + p) * 64 + co] = sum;
  }
}

// ---------------------------------------------------------------------------
// Conv partials -> LN -> KV proj (R13).  K [b][h][m][d], V^T [b][h][d][m].
__global__ __launch_bounds__(128) void k_lnkv(
    const float* __restrict__ part, const float* __restrict__ srb,
    const float* __restrict__ lng, const float* __restrict__ lnb,
    const float* __restrict__ kvw,
    _Float16* __restrict__ kbuf, _Float16* __restrict__ vbuf) {
  __shared__ __align__(16) float yn[64];
  __shared__ __align__(16) float4 lkvw[16][128];
  int p = blockIdx.x, t = threadIdx.x;
  for (int i = 0; i < 64; ++i) {
    int idx = i * 128 + t;
    int co2 = idx >> 6, ci = idx & 63;
    ((float*)lkvw)[(ci >> 2) * 512 + co2 * 4 + (ci & 3)] = kvw[idx];
  }
  if (t < 64) {
    float y = 0.f;
    for (int s = 0; s < 8; ++s) y += part[(s * 392 + p) * 64 + t];
    y += srb[t];
    float s1 = y, s2 = y * y;
#pragma unroll
    for (int off = 32; off; off >>= 1) { s1 += __shfl_xor(s1, off); s2 += __shfl_xor(s2, off); }
    float mean = s1 * 0.015625f;
    float var = s2 * 0.015625f - mean * mean;
    float rs = rsqrtf(var + 1e-5f);
    yn[t] = (y - mean) * rs * lng[t] + lnb[t];
  }
  __syncthreads();
  float acc = 0.f;
#pragma unroll
  for (int c4 = 0; c4 < 16; ++c4) {
    float4 w4 = lkvw[c4][t];
    float4 y4 = *(const float4*)&yn[c4 * 4];
    acc += y4.x * w4.x + y4.y * w4.y + y4.z * w4.z + y4.w * w4.w;
  }
  int b = p / 196, pi = p % 196;
  int h = (t & 63) >> 3, d = t & 7;
  if (t < 64) kbuf[((b * 8 + h) * 196 + pi) * 8 + d] = (_Float16)acc;
  else        vbuf[((b * 8 + h) * 8 + d) * 196 + pi] = (_Float16)acc;
}

// ---------------------------------------------------------------------------
// MFMA flash attention (R13 base, 64-row tiles, grid 392), LOW-LIVE-STATE:
// fused S-MFMA -> exp -> AV-MFMA per m-tile (no sacc[13]/pbf[13] arrays),
// dual AV accumulator chains (serial depth 13 -> 7), 2 ssum partials,
// pwh pre-staged.  Goal: VGPR ~120 -> 4 waves/SIMD latency hiding.
template <bool FINAL>
__global__ __launch_bounds__(512, 2) void k_score_out(
    const float* __restrict__ xqf, const float* __restrict__ qw,
    const _Float16* __restrict__ kbuf, const _Float16* __restrict__ vbuf,
    const uint* __restrict__ pwh, const float* __restrict__ pb,
    float* __restrict__ outp) {
  __shared__ __align__(16) uint sW[4096];        // [0,2048) qw*QSCALE; [2048,4096) pwh
  __shared__ __align__(16) uint sX[64 * 33];     // xq residual rows f16 pairs
  __shared__ __align__(16) uint lq[8 * 64 * 4];  // q f16 [h][row][8]
  __shared__ __align__(16) uint lo[64 * 34];     // o rows f16 pairs [row][c2]
  int blk = blockIdx.x;
  int b = blk / 196, tileb = blk % 196;
  int t = threadIdx.x;
  int h = t >> 6, l = t & 63;
  int r15 = l & 15, g = l >> 4;                  // fragment coords
  for (int i = t; i < 2048; i += 512) {
    int co = i & 63, c2 = i >> 6;
    float2 wv = *(const float2*)(qw + co * 64 + c2 * 2);
    sW[c2 * 64 + co] = h2u(pack2(wv.x * QSCALE, wv.y * QSCALE));
  }
  for (int i = t; i < 2048; i += 512) sW[2048 + i] = pwh[i];
  for (int i = t; i < 2048; i += 512) {
    int rr = i >> 5, c2 = i & 31;
    float2 v = *(const float2*)(xqf + ((size_t)b * NPIX + (size_t)tileb * 64 + rr) * 64 + c2 * 2);
    sX[rr * 33 + c2] = h2u(pack2(v.x, v.y));
  }
  __syncthreads();
  // scalar q-proj (R13 proven): thread (h, row=l) -> lq[h][row][0..7]
  {
    float q8[8];
#pragma unroll
    for (int j = 0; j < 8; ++j) q8[j] = 0.f;
#pragma unroll
    for (int c2 = 0; c2 < 32; ++c2) {
      half2_t xv = as_h2(sX[l * 33 + c2]);
      uint4 w0 = *(const uint4*)&sW[c2 * 64 + h * 8];
      uint4 w1 = *(const uint4*)&sW[c2 * 64 + h * 8 + 4];
      q8[0] = dot2acc(xv, as_h2(w0.x), q8[0]);
      q8[1] = dot2acc(xv, as_h2(w0.y), q8[1]);
      q8[2] = dot2acc(xv, as_h2(w0.z), q8[2]);
      q8[3] = dot2acc(xv, as_h2(w0.w), q8[3]);
      q8[4] = dot2acc(xv, as_h2(w1.x), q8[4]);
      q8[5] = dot2acc(xv, as_h2(w1.y), q8[5]);
      q8[6] = dot2acc(xv, as_h2(w1.z), q8[6]);
      q8[7] = dot2acc(xv, as_h2(w1.w), q8[7]);
    }
    uint4 qp;
    qp.x = h2u(pack2(q8[0], q8[1])); qp.y = h2u(pack2(q8[2], q8[3]));
    qp.z = h2u(pack2(q8[4], q8[5])); qp.w = h2u(pack2(q8[6], q8[7]));
    *(uint4*)&lq[(h * 64 + l) * 4] = qp;
  }
  __syncthreads();
  // K-frags / V^T-frags in VGPRs
  int bh = b * 8 + h;
  half4_t kf[13], vf[13];
#pragma unroll
  for (int tt = 0; tt < 13; ++tt) {
    int m = tt * 16 + r15;
    if (g < 2 && m < 196) {
      U2H4 u; u.u = *(const uint2*)(kbuf + ((size_t)bh * 196 + m) * 8 + 4 * g);
      kf[tt] = u.h;
    } else {
      kf[tt] = (half4_t)(_Float16)0.f;
    }
    int mv = tt * 16 + 4 * g;
    if (r15 < 8 && mv + 3 < 196) {
      U2H4 u; u.u = *(const uint2*)(vbuf + ((size_t)bh * 8 + r15) * 196 + mv);
      vf[tt] = u.h;
    } else {
      vf[tt] = (half4_t)(_Float16)0.f;
    }
  }
#pragma unroll 1
  for (int rt = 0; rt < 4; ++rt) {
    int rbase = rt * 16;
    half4_t qf;
    if (g < 2) {
      U2H4 u;
      u.u = *(const uint2*)&lq[(h * 64 + rbase + r15) * 4 + 2 * g];
      qf = u.h;
    } else {
      qf = (half4_t)(_Float16)0.f;
    }
    // fused S -> exp -> AV per m-tile; dual AV chains; 2 ssum partials
    float ss0 = 0.f, ss1 = 0.f;
    float4_t oacc0 = {0.f, 0.f, 0.f, 0.f};
    float4_t oacc1 = {0.f, 0.f, 0.f, 0.f};
#pragma unroll
    for (int tt = 0; tt < 13; ++tt) {
      float4_t z = {0.f, 0.f, 0.f, 0.f};
      float4_t sc = mfma16(kf[tt], qf, z);
      float e0, e1, e2, e3;
      if (tt == 12 && g > 0) {
        e0 = e1 = e2 = e3 = 0.f;
      } else {
        e0 = fexp2(sc[0]); e1 = fexp2(sc[1]);
        e2 = fexp2(sc[2]); e3 = fexp2(sc[3]);
      }
      if (tt & 1) ss1 += (e0 + e1) + (e2 + e3);
      else        ss0 += (e0 + e1) + (e2 + e3);
      half2_t p01 = pack2(e0, e1), p23 = pack2(e2, e3);
      half4_t pv; pv.x = p01.x; pv.y = p01.y; pv.z = p23.x; pv.w = p23.y;
      if (tt & 1) oacc1 = mfma16(vf[tt], pv, oacc1);
      else        oacc0 = mfma16(vf[tt], pv, oacc0);
    }
    float ssum = ss0 + ss1;
    ssum += __shfl_xor(ssum, 16);
    ssum += __shfl_xor(ssum, 32);
    float rl = 1.f / ssum;
    if (g < 2) {
      uint2 ov;
      ov.x = h2u(pack2((oacc0[0] + oacc1[0]) * rl, (oacc0[1] + oacc1[1]) * rl));
      ov.y = h2u(pack2((oacc0[2] + oacc1[2]) * rl, (oacc0[3] + oacc1[3]) * rl));
      *(uint2*)&lo[(rbase + r15) * 34 + h * 4 + 2 * g] = ov;
    }
  }
  __syncthreads();
  // residual + out-proj: thread (r2 = t>>3, cq = t&7) -> co = cq*8..+7
  int r2 = t >> 3, cq = t & 7;
  size_t gr2 = (size_t)b * NPIX + (size_t)tileb * 64 + r2;
  float acc[8];
#pragma unroll
  for (int k = 0; k < 8; ++k) acc[k] = pb[cq * 8 + k];
#pragma unroll
  for (int c2 = 0; c2 < 32; ++c2) {
    half2_t sv = as_h2(lo[r2 * 34 + c2]) + as_h2(sX[r2 * 33 + c2]);
    uint4 w0 = *(const uint4*)&sW[2048 + c2 * 64 + cq * 8];
    uint4 w1 = *(const uint4*)&sW[2048 + c2 * 64 + cq * 8 + 4];
    acc[0] = dot2acc(sv, as_h2(w0.x), acc[0]);
    acc[1] = dot2acc(sv, as_h2(w0.y), acc[1]);
    acc[2] = dot2acc(sv, as_h2(w0.z), acc[2]);
    acc[3] = dot2acc(sv, as_h2(w0.w), acc[3]);
    acc[4] = dot2acc(sv, as_h2(w1.x), acc[4]);
    acc[5] = dot2acc(sv, as_h2(w1.y), acc[5]);
    acc[6] = dot2acc(sv, as_h2(w1.z), acc[6]);
    acc[7] = dot2acc(sv, as_h2(w1.w), acc[7]);
  }
  if (!FINAL) {
    float4 v0, v1;
    v0.x = acc[0]; v0.y = acc[1]; v0.z = acc[2]; v0.w = acc[3];
    v1.x = acc[4]; v1.y = acc[5]; v1.z = acc[6]; v1.w = acc[7];
    float* orow = outp + gr2 * 64 + cq * 8;
    *(float4*)orow = v0;
    *(float4*)(orow + 4) = v1;
  } else {
    __syncthreads();
    uint2 p0, p1;
    p0.x = h2u(pack2(acc[0], acc[1])); p0.y = h2u(pack2(acc[2], acc[3]));
    p1.x = h2u(pack2(acc[4], acc[5])); p1.y = h2u(pack2(acc[6], acc[7]));
    *(uint2*)&lo[r2 * 34 + cq * 4] = p0;
    *(uint2*)&lo[r2 * 34 + cq * 4 + 2] = p1;
    __syncthreads();
    for (int i = t; i < 4096; i += 512) {
      int c = i >> 6, rr = i & 63;
      half2_t pr = as_h2(lo[rr * 34 + (c >> 1)]);
      float val = (c & 1) ? (float)pr.y : (float)pr.x;
      outp[((size_t)(b * 64 + c)) * NPIX + (size_t)tileb * 64 + rr] = val;
    }
  }
}

// ---------------------------------------------------------------------------
extern "C" void kernel_launch(void* const* d_in, const int* in_sizes, int n_in,
                              void* d_out, int out_size, void* d_ws, size_t ws_size,
                              hipStream_t stream) {
  const float* x1 = (const float*)d_in[0];
  const float* x2 = (const float*)d_in[1];
  const float *qw[4], *kvw[4], *pwv[4], *pbv[4], *srw[4], *srb[4], *lng[4], *lnb[4];
  for (int i = 0; i < 4; ++i) {
    const int base = 2 + i * 8;
    qw[i]  = (const float*)d_in[base + 0];
    kvw[i] = (const float*)d_in[base + 1];
    pwv[i] = (const float*)d_in[base + 2];
    pbv[i] = (const float*)d_in[base + 3];
    srw[i] = (const float*)d_in[base + 4];
    srb[i] = (const float*)d_in[base + 5];
    lng[i] = (const float*)d_in[base + 6];
    lnb[i] = (const float*)d_in[base + 7];
  }
  const float* fpw = (const float*)d_in[34];
  const float* fpb = (const float*)d_in[35];
  float* out = (float*)d_out;

  char* ws = (char*)d_ws;
  const size_t SZ = (size_t)2 * NPIX * 64 * 4;       // 6,422,528 B
  float* slot0 = (float*)(ws);
  float* slot1 = (float*)(ws + SZ);
  float* slot2 = (float*)(ws + 2 * SZ);
  size_t off = 3 * SZ;
  float* wt    = (float*)(ws + off); off += 4u * 1048576;
  float* part  = (float*)(ws + off); off += 802816;
  _Float16* kbuf = (_Float16*)(ws + off); off += 50176;
  _Float16* vbuf = (_Float16*)(ws + off); off += 50176;
  uint* pwh    = (uint*)(ws + off); off += 4 * 2048 * 4;
  float* pbc   = (float*)(ws + off); off += 256;

  float* xf1 = slot0; float* xf2 = slot1;
  float* abuf = slot2; float* bbuf = slot0; float* cbuf = slot1;

  k_prep<<<1044, 256, 0, stream>>>(x1, x2, xf1, xf2,
                                   srw[0], srw[1], srw[2], srw[3], wt,
                                   fpw, fpb, pwv[3], pbv[3],
                                   pwv[0], pwv[1], pwv[2], pwh, pbc);

  const float* xqs[4] = {xf1, xf2, bbuf, abuf};
  const float* kvs[4] = {xf1, abuf, bbuf, cbuf};
  float* outs[3]      = {abuf, bbuf, cbuf};
  for (int i = 0; i < 4; ++i) {
    k_conv<<<392, 256, 0, stream>>>(kvs[i], wt + i * 262144, part);
    k_lnkv<<<392, 128, 0, stream>>>(part, srb[i], lng[i], lnb[i], kvw[i], kbuf, vbuf);
    if (i < 3)
      k_score_out<false><<<392, 512, 0, stream>>>(xqs[i], qw[i], kbuf, vbuf,
                                                  pwh + i * 2048, pbv[i], outs[i]);
    else
      k_score_out<true><<<392, 512, 0, stream>>>(xqs[3], qw[3], kbuf, vbuf,
                                                 pwh + 3 * 2048, pbc, out);
  }
}

// Round 21
// 146.815 us; speedup vs baseline: 1.0900x; 1.0900x over previous
//
#include <hip/hip_runtime.h>
#include <hip/hip_bf16.h>

// Problem constants
#define NPIX 12544   // 112*112
#define NKV 196      // 14*14
#define CCH 64

typedef _Float16 half2_t __attribute__((ext_vector_type(2)));
typedef _Float16 half4_t __attribute__((ext_vector_type(4)));
typedef float float4_t __attribute__((ext_vector_type(4)));
typedef __fp16 fp16v2_t __attribute__((ext_vector_type(2)));

#if defined(__has_builtin)
#if __has_builtin(__builtin_amdgcn_fdot2)
#define HAVE_FDOT2 1
#endif
#if __has_builtin(__builtin_amdgcn_cvt_pkrtz)
#define HAVE_PKRTZ 1
#endif
#if __has_builtin(__builtin_amdgcn_exp2f)
#define HAVE_EXP2 1
#endif
#if __has_builtin(__builtin_amdgcn_mfma_f32_16x16x16f16)
#define HAVE_MFMA16 1
#endif
#endif

__device__ __forceinline__ float dot2acc(half2_t a, half2_t b, float c) {
#ifdef HAVE_FDOT2
  return __builtin_amdgcn_fdot2(a, b, c, false);
#else
  return c + (float)a.x * (float)b.x + (float)a.y * (float)b.y;
#endif
}

__device__ __forceinline__ half2_t pack2(float a, float b) {
#ifdef HAVE_PKRTZ
  union { fp16v2_t r; half2_t h; } u;
  u.r = __builtin_amdgcn_cvt_pkrtz(a, b);
  return u.h;
#else
  half2_t v; v.x = (_Float16)a; v.y = (_Float16)b; return v;
#endif
}

__device__ __forceinline__ half2_t as_h2(uint u) {
  union { uint v; half2_t h; } c; c.v = u; return c.h;
}
__device__ __forceinline__ uint h2u(half2_t h) {
  union { half2_t h; uint v; } c; c.h = h; return c.v;
}
__device__ __forceinline__ float fexp2(float x) {
#ifdef HAVE_EXP2
  return __builtin_amdgcn_exp2f(x);
#else
  return exp2f(x);
#endif
}

__device__ __forceinline__ float4_t mfma16(half4_t a, half4_t b, float4_t c) {
#ifdef HAVE_MFMA16
  return __builtin_amdgcn_mfma_f32_16x16x16f16(a, b, c, 0, 0, 0);
#else
  asm volatile("v_mfma_f32_16x16x16_f16 %0, %1, %2, %0" : "+v"(c) : "v"(a), "v"(b));
  return c;
#endif
}

union U2H4 { uint2 u; half4_t h; };

// q scale: hd^-0.5 * log2(e) so the softmax can use raw exp2 (v_exp_f32)
#define QSCALE 0.5100974012336431f

// ---------------------------------------------------------------------------
// Prep kernel (R13 exact):
//   blocks 0..783    transpose x1/x2 [B,C,HW]->[B,HW,C]
//   blocks 784..1039 srw [co][ci][ij] -> wt [ij][ci][co] (f32)
//   block 1040       combined final weights (fpw@pw4) -> pwh[3] (f16) + pbc
//   blocks 1041..1043 pwv[a] -> pwh[a] f16 packed [c2][co]
__global__ __launch_bounds__(256) void k_prep(
    const float* __restrict__ x1, const float* __restrict__ x2,
    float* __restrict__ x1f, float* __restrict__ x2f,
    const float* __restrict__ s0, const float* __restrict__ s1,
    const float* __restrict__ s2, const float* __restrict__ s3,
    float* __restrict__ wt,
    const float* __restrict__ fpw, const float* __restrict__ fpb,
    const float* __restrict__ pw4, const float* __restrict__ pb4,
    const float* __restrict__ pw0, const float* __restrict__ pw1,
    const float* __restrict__ pw2,
    uint* __restrict__ pwh, float* __restrict__ pbc) {
  __shared__ float smem[2 * 64 * 65 + 64];
  int blk = blockIdx.x, t = threadIdx.x;
  float (*tile)[65] = (float(*)[65])smem;
  if (blk < 784) {
    int tensor = blk / 392; int rem = blk - tensor * 392;
    int b = rem / 196; int t64 = rem % 196; int n0 = t64 * 64;
    const float* src = tensor ? x2 : x1;
    float* dst = tensor ? x2f : x1f;
    for (int i = 0; i < 16; ++i) {
      int c = i * 4 + (t >> 6);
      int n = t & 63;
      tile[c][n] = src[(b * 64 + c) * NPIX + n0 + n];
    }
    __syncthreads();
    for (int i = 0; i < 16; ++i) {
      int n = i * 4 + (t >> 6);
      int c = t & 63;
      dst[(b * NPIX + n0 + n) * 64 + c] = tile[c][n];
    }
  } else if (blk < 1040) {
    int id = blk - 784; int a = id >> 6; int ci = id & 63;
    const float* s = (a == 0) ? s0 : (a == 1) ? s1 : (a == 2) ? s2 : s3;
    float* d = wt + a * 262144;
    for (int i = 0; i < 16; ++i) {
      int co = i * 4 + (t >> 6);
      int ij = t & 63;
      tile[co][ij] = s[co * 4096 + ci * 64 + ij];
    }
    __syncthreads();
    for (int i = 0; i < 16; ++i) {
      int ij = i * 4 + (t >> 6);
      int co = t & 63;
      d[(ij * 64 + ci) * 64 + co] = tile[co][ij];
    }
  } else if (blk == 1040) {
    float (*A)[65] = (float(*)[65])smem;
    float (*B)[65] = (float(*)[65])(smem + 4160);
    float* bb = smem + 8320;
    for (int i = 0; i < 16; ++i) {
      int idx = i * 256 + t;
      A[idx >> 6][idx & 63] = fpw[idx];
      B[idx >> 6][idx & 63] = pw4[idx];
    }
    if (t < 64) bb[t] = pb4[t];
    __syncthreads();
    int i = t >> 2, jq = t & 3;
    float acc[16];
#pragma unroll
    for (int jj = 0; jj < 16; ++jj) acc[jj] = 0.f;
    for (int k = 0; k < 64; ++k) {
      float a = A[i][k];
#pragma unroll
      for (int jj = 0; jj < 16; ++jj) acc[jj] += a * B[k][jq * 16 + jj];
    }
#pragma unroll
    for (int m = 0; m < 8; ++m)
      pwh[3 * 2048 + (jq * 8 + m) * 64 + i] = h2u(pack2(acc[2 * m], acc[2 * m + 1]));
    if (t < 64) {
      float s = fpb[t];
      for (int k = 0; k < 64; ++k) s += A[t][k] * bb[k];
      pbc[t] = s;
    }
  } else {
    int a = blk - 1041;
    const float* pw = (a == 0) ? pw0 : (a == 1) ? pw1 : pw2;
    for (int i = 0; i < 8; ++i) {
      int idx = i * 256 + t;
      int co = idx & 63, c2 = idx >> 6;
      float2 wv = *(const float2*)(pw + co * 64 + c2 * 2);
      pwh[a * 2048 + c2 * 64 + co] = h2u(pack2(wv.x, wv.y));
    }
  }
}

// ---------------------------------------------------------------------------
// Reduction conv as GEMM partials (R13 exact).  grid = 49 groups * 8 k-slices.
__global__ __launch_bounds__(256) void k_conv(
    const float* __restrict__ xf, const float* __restrict__ wt,
    float* __restrict__ part) {
  __shared__ __align__(16) float act[8 * 8 * 72];
  __shared__ float red[16][8][65];
  int g = blockIdx.x % 49, s = blockIdx.x / 49;
  int t = threadIdx.x;
  for (int q = 0; q < 5; ++q) {
    int fi = q * 256 + t;
    if (fi < 1152) {
      int row = fi / 18, pos = fi % 18;
      if (pos < 16) {
        int pix = row >> 3, ijl = row & 7;
        int ij = s * 8 + ijl, ii = ij >> 3, jj = ij & 7;
        int p = g * 8 + pix, b = p / 196, pi = p % 196;
        int py = pi / 14, px = pi % 14;
        *(float4*)&act[row * 72 + pos * 4] =
            *(const float4*)(xf + (size_t)(b * NPIX + (8 * py + ii) * 112 + 8 * px + jj) * 64 + pos * 4);
      }
    }
  }
  __syncthreads();
  int coq = t & 15, kp = t >> 4;
  int ijl = kp >> 1, ci0 = (kp & 1) * 32;
  float acc[8][4];
#pragma unroll
  for (int p = 0; p < 8; ++p)
#pragma unroll
    for (int c = 0; c < 4; ++c) acc[p][c] = 0.f;
  const float* wb = wt + ((s * 8 + ijl) * 64 + ci0) * 64 + coq * 4;
  const float* ab = act + ijl * 72 + ci0;
  for (int kk = 0; kk < 32; ++kk) {
    float4 w4 = *(const float4*)(wb + kk * 64);
#pragma unroll
    for (int p = 0; p < 8; ++p) {
      float a = ab[p * 576 + kk];
      acc[p][0] += a * w4.x; acc[p][1] += a * w4.y;
      acc[p][2] += a * w4.z; acc[p][3] += a * w4.w;
    }
  }
#pragma unroll
  for (int p = 0; p < 8; ++p)
#pragma unroll
    for (int c = 0; c < 4; ++c) red[kp][p][coq * 4 + c] = acc[p][c];
  __syncthreads();
  for (int q = 0; q < 2; ++q) {
    int oi = t + q * 256;
    int pix = oi >> 6, co = oi & 63;
    float sum = 0.f;
#pragma unroll
    for (int k = 0; k < 16; ++k) sum += red[k][pix][co];
    int p = g * 8 + pix;
    part[(s * 392 + p) * 64 + co] = sum;
  }
}

// ---------------------------------------------------------------------------
// Conv partials -> LN -> KV proj (R13 exact).  K [b][h][m][d], V^T [b][h][d][m].
__global__ __launch_bounds__(128) void k_lnkv(
    const float* __restrict__ part, const float* __restrict__ srb,
    const float* __restrict__ lng, const float* __restrict__ lnb,
    const float* __restrict__ kvw,
    _Float16* __restrict__ kbuf, _Float16* __restrict__ vbuf) {
  __shared__ __align__(16) float yn[64];
  __shared__ __align__(16) float4 lkvw[16][128];
  int p = blockIdx.x, t = threadIdx.x;
  for (int i = 0; i < 64; ++i) {
    int idx = i * 128 + t;
    int co2 = idx >> 6, ci = idx & 63;
    ((float*)lkvw)[(ci >> 2) * 512 + co2 * 4 + (ci & 3)] = kvw[idx];
  }
  if (t < 64) {
    float y = 0.f;
    for (int s = 0; s < 8; ++s) y += part[(s * 392 + p) * 64 + t];
    y += srb[t];
    float s1 = y, s2 = y * y;
#pragma unroll
    for (int off = 32; off; off >>= 1) { s1 += __shfl_xor(s1, off); s2 += __shfl_xor(s2, off); }
    float mean = s1 * 0.015625f;
    float var = s2 * 0.015625f - mean * mean;
    float rs = rsqrtf(var + 1e-5f);
    yn[t] = (y - mean) * rs * lng[t] + lnb[t];
  }
  __syncthreads();
  float acc = 0.f;
#pragma unroll
  for (int c4 = 0; c4 < 16; ++c4) {
    float4 w4 = lkvw[c4][t];
    float4 y4 = *(const float4*)&yn[c4 * 4];
    acc += y4.x * w4.x + y4.y * w4.y + y4.z * w4.z + y4.w * w4.w;
  }
  int b = p / 196, pi = p % 196;
  int h = (t & 63) >> 3, d = t & 7;
  if (t < 64) kbuf[((b * 8 + h) * 196 + pi) * 8 + d] = (_Float16)acc;
  else        vbuf[((b * 8 + h) * 8 + d) * 196 + pi] = (_Float16)acc;
}

// ---------------------------------------------------------------------------
// MFMA flash attention + q-proj + residual + out-proj (R13 exact).
// grid = 2b * 196 (64-row chunks) = 392 blocks, 512 thr = 8 waves = 8 heads.
// Swapped products: every fragment lane-local (zero cross-lane moves).
// LDS 33.1 KB -> 4 blocks/CU (thread-limited); phase-separated sacc loop
// lets the 13 independent S-MFMAs pipeline.
template <bool FINAL>
__global__ __launch_bounds__(512, 2) void k_score_out(
    const float* __restrict__ xqf, const float* __restrict__ qw,
    const _Float16* __restrict__ kbuf, const _Float16* __restrict__ vbuf,
    const uint* __restrict__ pwh, const float* __restrict__ pb,
    float* __restrict__ outp) {
  __shared__ __align__(16) uint sW[2048];        // qw then pwh (f16 pairs)
  __shared__ __align__(16) uint sX[64 * 33];     // xq residual rows f16 pairs
  __shared__ __align__(16) uint lq[8 * 64 * 4];  // q f16 [h][row][8]
  __shared__ __align__(16) uint lo[64 * 34];     // o rows f16 pairs [row][c2]
  int blk = blockIdx.x;
  int b = blk / 196, tileb = blk % 196;
  int t = threadIdx.x;
  int h = t >> 6, l = t & 63;
  int r15 = l & 15, g = l >> 4;                  // fragment coords
  for (int i = t; i < 2048; i += 512) {
    int co = i & 63, c2 = i >> 6;
    float2 wv = *(const float2*)(qw + co * 64 + c2 * 2);
    sW[c2 * 64 + co] = h2u(pack2(wv.x * QSCALE, wv.y * QSCALE));
  }
  for (int i = t; i < 2048; i += 512) {
    int rr = i >> 5, c2 = i & 31;
    float2 v = *(const float2*)(xqf + ((size_t)b * NPIX + (size_t)tileb * 64 + rr) * 64 + c2 * 2);
    sX[rr * 33 + c2] = h2u(pack2(v.x, v.y));
  }
  __syncthreads();
  // q-proj
  {
    float q8[8];
#pragma unroll
    for (int j = 0; j < 8; ++j) q8[j] = 0.f;
#pragma unroll
    for (int c2 = 0; c2 < 32; ++c2) {
      half2_t xv = as_h2(sX[l * 33 + c2]);
      uint4 w0 = *(const uint4*)&sW[c2 * 64 + h * 8];
      uint4 w1 = *(const uint4*)&sW[c2 * 64 + h * 8 + 4];
      q8[0] = dot2acc(xv, as_h2(w0.x), q8[0]);
      q8[1] = dot2acc(xv, as_h2(w0.y), q8[1]);
      q8[2] = dot2acc(xv, as_h2(w0.z), q8[2]);
      q8[3] = dot2acc(xv, as_h2(w0.w), q8[3]);
      q8[4] = dot2acc(xv, as_h2(w1.x), q8[4]);
      q8[5] = dot2acc(xv, as_h2(w1.y), q8[5]);
      q8[6] = dot2acc(xv, as_h2(w1.z), q8[6]);
      q8[7] = dot2acc(xv, as_h2(w1.w), q8[7]);
    }
    uint4 qp;
    qp.x = h2u(pack2(q8[0], q8[1])); qp.y = h2u(pack2(q8[2], q8[3]));
    qp.z = h2u(pack2(q8[4], q8[5])); qp.w = h2u(pack2(q8[6], q8[7]));
    *(uint4*)&lq[(h * 64 + l) * 4] = qp;
  }
  __syncthreads();
  // K-frags / V^T-frags in VGPRs
  int bh = b * 8 + h;
  half4_t kf[13], vf[13];
#pragma unroll
  for (int tt = 0; tt < 13; ++tt) {
    int m = tt * 16 + r15;
    if (g < 2 && m < 196) {
      U2H4 u; u.u = *(const uint2*)(kbuf + ((size_t)bh * 196 + m) * 8 + 4 * g);
      kf[tt] = u.h;
    } else {
      kf[tt] = (half4_t)(_Float16)0.f;
    }
    int mv = tt * 16 + 4 * g;
    if (r15 < 8 && mv + 3 < 196) {
      U2H4 u; u.u = *(const uint2*)(vbuf + ((size_t)bh * 8 + r15) * 196 + mv);
      vf[tt] = u.h;
    } else {
      vf[tt] = (half4_t)(_Float16)0.f;
    }
  }
#pragma unroll 1
  for (int rt = 0; rt < 4; ++rt) {
    int rbase = rt * 16;
    half4_t qf;
    if (g < 2) {
      U2H4 u;
      u.u = *(const uint2*)&lq[(h * 64 + rbase + r15) * 4 + 2 * g];
      qf = u.h;
    } else {
      qf = (half4_t)(_Float16)0.f;
    }
    float4_t sacc[13];
#pragma unroll
    for (int tt = 0; tt < 13; ++tt) {
      float4_t z = {0.f, 0.f, 0.f, 0.f};
      sacc[tt] = mfma16(kf[tt], qf, z);
    }
    float ssum = 0.f;
    half4_t pbf[13];
#pragma unroll
    for (int tt = 0; tt < 13; ++tt) {
      float e0, e1, e2, e3;
      if (tt == 12 && g > 0) {
        e0 = e1 = e2 = e3 = 0.f;
      } else {
        e0 = fexp2(sacc[tt][0]); e1 = fexp2(sacc[tt][1]);
        e2 = fexp2(sacc[tt][2]); e3 = fexp2(sacc[tt][3]);
      }
      ssum += (e0 + e1) + (e2 + e3);
      half2_t p01 = pack2(e0, e1), p23 = pack2(e2, e3);
      half4_t pv; pv.x = p01.x; pv.y = p01.y; pv.z = p23.x; pv.w = p23.y;
      pbf[tt] = pv;
    }
    ssum += __shfl_xor(ssum, 16);
    ssum += __shfl_xor(ssum, 32);
    float rl = 1.f / ssum;
    float4_t oacc = {0.f, 0.f, 0.f, 0.f};
#pragma unroll
    for (int tt = 0; tt < 13; ++tt) oacc = mfma16(vf[tt], pbf[tt], oacc);
    if (g < 2) {
      uint2 ov;
      ov.x = h2u(pack2(oacc[0] * rl, oacc[1] * rl));
      ov.y = h2u(pack2(oacc[2] * rl, oacc[3] * rl));
      *(uint2*)&lo[(rbase + r15) * 34 + h * 4 + 2 * g] = ov;
    }
  }
  __syncthreads();
  for (int i = t; i < 2048; i += 512) sW[i] = pwh[i];
  __syncthreads();
  int r2 = t >> 3, cq = t & 7;
  size_t gr2 = (size_t)b * NPIX + (size_t)tileb * 64 + r2;
  float acc[8];
#pragma unroll
  for (int k = 0; k < 8; ++k) acc[k] = pb[cq * 8 + k];
#pragma unroll
  for (int c2 = 0; c2 < 32; ++c2) {
    half2_t sv = as_h2(lo[r2 * 34 + c2]) + as_h2(sX[r2 * 33 + c2]);
    uint4 w0 = *(const uint4*)&sW[c2 * 64 + cq * 8];
    uint4 w1 = *(const uint4*)&sW[c2 * 64 + cq * 8 + 4];
    acc[0] = dot2acc(sv, as_h2(w0.x), acc[0]);
    acc[1] = dot2acc(sv, as_h2(w0.y), acc[1]);
    acc[2] = dot2acc(sv, as_h2(w0.z), acc[2]);
    acc[3] = dot2acc(sv, as_h2(w0.w), acc[3]);
    acc[4] = dot2acc(sv, as_h2(w1.x), acc[4]);
    acc[5] = dot2acc(sv, as_h2(w1.y), acc[5]);
    acc[6] = dot2acc(sv, as_h2(w1.z), acc[6]);
    acc[7] = dot2acc(sv, as_h2(w1.w), acc[7]);
  }
  if (!FINAL) {
    float4 v0, v1;
    v0.x = acc[0]; v0.y = acc[1]; v0.z = acc[2]; v0.w = acc[3];
    v1.x = acc[4]; v1.y = acc[5]; v1.z = acc[6]; v1.w = acc[7];
    float* orow = outp + gr2 * 64 + cq * 8;
    *(float4*)orow = v0;
    *(float4*)(orow + 4) = v1;
  } else {
    __syncthreads();
    uint2 p0, p1;
    p0.x = h2u(pack2(acc[0], acc[1])); p0.y = h2u(pack2(acc[2], acc[3]));
    p1.x = h2u(pack2(acc[4], acc[5])); p1.y = h2u(pack2(acc[6], acc[7]));
    *(uint2*)&lo[r2 * 34 + cq * 4] = p0;
    *(uint2*)&lo[r2 * 34 + cq * 4 + 2] = p1;
    __syncthreads();
    for (int i = t; i < 4096; i += 512) {
      int c = i >> 6, rr = i & 63;
      half2_t pr = as_h2(lo[rr * 34 + (c >> 1)]);
      float val = (c & 1) ? (float)pr.y : (float)pr.x;
      outp[((size_t)(b * 64 + c)) * NPIX + (size_t)tileb * 64 + rr] = val;
    }
  }
}

// ---------------------------------------------------------------------------
extern "C" void kernel_launch(void* const* d_in, const int* in_sizes, int n_in,
                              void* d_out, int out_size, void* d_ws, size_t ws_size,
                              hipStream_t stream) {
  const float* x1 = (const float*)d_in[0];
  const float* x2 = (const float*)d_in[1];
  const float *qw[4], *kvw[4], *pwv[4], *pbv[4], *srw[4], *srb[4], *lng[4], *lnb[4];
  for (int i = 0; i < 4; ++i) {
    const int base = 2 + i * 8;
    qw[i]  = (const float*)d_in[base + 0];
    kvw[i] = (const float*)d_in[base + 1];
    pwv[i] = (const float*)d_in[base + 2];
    pbv[i] = (const float*)d_in[base + 3];
    srw[i] = (const float*)d_in[base + 4];
    srb[i] = (const float*)d_in[base + 5];
    lng[i] = (const float*)d_in[base + 6];
    lnb[i] = (const float*)d_in[base + 7];
  }
  const float* fpw = (const float*)d_in[34];
  const float* fpb = (const float*)d_in[35];
  float* out = (float*)d_out;

  char* ws = (char*)d_ws;
  const size_t SZ = (size_t)2 * NPIX * 64 * 4;       // 6,422,528 B
  float* slot0 = (float*)(ws);
  float* slot1 = (float*)(ws + SZ);
  float* slot2 = (float*)(ws + 2 * SZ);
  size_t off = 3 * SZ;
  float* wt    = (float*)(ws + off); off += 4u * 1048576;
  float* part  = (float*)(ws + off); off += 802816;
  _Float16* kbuf = (_Float16*)(ws + off); off += 50176;
  _Float16* vbuf = (_Float16*)(ws + off); off += 50176;
  uint* pwh    = (uint*)(ws + off); off += 4 * 2048 * 4;
  float* pbc   = (float*)(ws + off); off += 256;

  float* xf1 = slot0; float* xf2 = slot1;
  float* abuf = slot2; float* bbuf = slot0; float* cbuf = slot1;

  k_prep<<<1044, 256, 0, stream>>>(x1, x2, xf1, xf2,
                                   srw[0], srw[1], srw[2], srw[3], wt,
                                   fpw, fpb, pwv[3], pbv[3],
                                   pwv[0], pwv[1], pwv[2], pwh, pbc);

  const float* xqs[4] = {xf1, xf2, bbuf, abuf};
  const float* kvs[4] = {xf1, abuf, bbuf, cbuf};
  float* outs[3]      = {abuf, bbuf, cbuf};
  for (int i = 0; i < 4; ++i) {
    k_conv<<<392, 256, 0, stream>>>(kvs[i], wt + i * 262144, part);
    k_lnkv<<<392, 128, 0, stream>>>(part, srb[i], lng[i], lnb[i], kvw[i], kbuf, vbuf);
    if (i < 3)
      k_score_out<false><<<392, 512, 0, stream>>>(xqs[i], qw[i], kbuf, vbuf,
                                                  pwh + i * 2048, pbv[i], outs[i]);
    else
      k_score_out<true><<<392, 512, 0, stream>>>(xqs[3], qw[3], kbuf, vbuf,
                                                 pwh + 3 * 2048, pbc, out);
  }
}